// Round 10
// baseline (51.153 us; speedup 1.0000x reference)
//
#include <hip/hip_runtime.h>

// CharacteristicLineEncoder: B=4096, DIM=3, L=300, S=60, P=5, E=128
// out[b,s,e] = sum_p W_lr[s,p]*relu(W_le[e,:]·x[b,:,5s+p] + b_le[e]) + b_lr[s]
//            + relu( sum_l W_gn[l]*relu(W_ge[e,:]·x[b,:,l] + b_ge[e]) + b_gn )
//
// 256 threads = 4 waves per b; lane owns e-pair {2*lane, 2*lane+1} (one wave
// covers all 128 e -> minimal broadcast-LDS instructions, R8 lesson).
// FUSED single sweep (R9->R10): wave wq owns l-quarter 80wq.. == regions
// 16wq.. , so each x-quad is ds_read ONCE and feeds BOTH branches -> LDS
// instructions halved (R9 lesson: broadcast ds_read_b128 ~12cyc each is the
// bottleneck pipe). Weight indices built from readfirstlane'd wq + loop
// constants -> provably wave-uniform -> s_load path (R6 lesson). Natural
// register allocation — no min-waves arg (R4/R5 spill lesson).

#define RELU(v) fmaxf((v), 0.0f)

__global__ __launch_bounds__(256) void cle_kernel(
    const float* __restrict__ x,     // [B,3,300]
    const float* __restrict__ W_le,  // [E,3]
    const float* __restrict__ b_le,  // [E]
    const float* __restrict__ W_lr,  // [300]
    const float* __restrict__ b_lr,  // [60]
    const float* __restrict__ W_ge,  // [E,3]
    const float* __restrict__ b_ge,  // [E]
    const float* __restrict__ W_gn,  // [300]
    const float* __restrict__ b_gn,  // [1]
    float* __restrict__ out)         // [B,60,128]
{
    const int tid  = threadIdx.x;
    const int lane = tid & 63;
    const int wq   = __builtin_amdgcn_readfirstlane(tid >> 6);  // wave 0..3, SGPR
    const int b    = blockIdx.x;
    const int e0   = lane << 1;      // this lane's e-pair

    __shared__ __align__(16) float4 sx4[225];  // x[b]: channel c, quad j at [c*75+j]
    __shared__ float2 sgp[4][64];              // per-wave global-branch partials

    // ---- stage x[b] (3.6 KB), coalesced float4 ----
    if (tid < 225) sx4[tid] = ((const float4*)(x + (size_t)b * 900))[tid];

    // per-lane (e-pair) weights
    const float wg00 = W_ge[e0 * 3 + 0], wg01 = W_ge[e0 * 3 + 1], wg02 = W_ge[e0 * 3 + 2];
    const float wg10 = W_ge[e0 * 3 + 3], wg11 = W_ge[e0 * 3 + 4], wg12 = W_ge[e0 * 3 + 5];
    const float bg0 = b_ge[e0], bg1 = b_ge[e0 + 1];
    const float wl00 = W_le[e0 * 3 + 0], wl01 = W_le[e0 * 3 + 1], wl02 = W_le[e0 * 3 + 2];
    const float wl10 = W_le[e0 * 3 + 3], wl11 = W_le[e0 * 3 + 4], wl12 = W_le[e0 * 3 + 5];
    const float bl0 = b_le[e0], bl1 = b_le[e0 + 1];
    const float bgn = b_gn[0];

    __syncthreads();

    // ---- fused sweep over this wave's quads: global + local together ----
    float ga0 = 0.f, ga1 = 0.f, ga2 = 0.f, ga3 = 0.f;   // global, e0
    float gb0 = 0.f, gb1 = 0.f, gb2 = 0.f, gb3 = 0.f;   // global, e1
    float la0[16], la1[16];                              // local accs, e0/e1
#pragma unroll
    for (int i = 0; i < 16; ++i) { la0[i] = 0.0f; la1[i] = 0.0f; }

#define GE0(cmp) RELU(fmaf(wg02, c2.cmp, fmaf(wg01, c1.cmp, fmaf(wg00, c0.cmp, bg0))))
#define GE1(cmp) RELU(fmaf(wg12, c2.cmp, fmaf(wg11, c1.cmp, fmaf(wg10, c0.cmp, bg1))))
#define LE0(cmp) RELU(fmaf(wl02, c2.cmp, fmaf(wl01, c1.cmp, fmaf(wl00, c0.cmp, bl0))))
#define LE1(cmp) RELU(fmaf(wl12, c2.cmp, fmaf(wl11, c1.cmp, fmaf(wl10, c0.cmp, bl1))))
    // one quad = 4 l: read c0,c1,c2 ONCE, feed both branches
#define DOQ(qi, R0, R1, R2, R3)                                                \
    {                                                                          \
        const int qq = q0 + (qi);                                              \
        const int lw = qq * 4;            /* uniform -> scalarizes */          \
        const float4 c0 = sx4[qq], c1 = sx4[75 + qq], c2 = sx4[150 + qq];      \
        ga0 = fmaf(W_gn[lw + 0], GE0(x), ga0);                                 \
        gb0 = fmaf(W_gn[lw + 0], GE1(x), gb0);                                 \
        ga1 = fmaf(W_gn[lw + 1], GE0(y), ga1);                                 \
        gb1 = fmaf(W_gn[lw + 1], GE1(y), gb1);                                 \
        ga2 = fmaf(W_gn[lw + 2], GE0(z), ga2);                                 \
        gb2 = fmaf(W_gn[lw + 2], GE1(z), gb2);                                 \
        ga3 = fmaf(W_gn[lw + 3], GE0(w), ga3);                                 \
        gb3 = fmaf(W_gn[lw + 3], GE1(w), gb3);                                 \
        la0[R0] = fmaf(W_lr[lw + 0], LE0(x), la0[R0]);                         \
        la1[R0] = fmaf(W_lr[lw + 0], LE1(x), la1[R0]);                         \
        la0[R1] = fmaf(W_lr[lw + 1], LE0(y), la0[R1]);                         \
        la1[R1] = fmaf(W_lr[lw + 1], LE1(y), la1[R1]);                         \
        la0[R2] = fmaf(W_lr[lw + 2], LE0(z), la0[R2]);                         \
        la1[R2] = fmaf(W_lr[lw + 2], LE1(z), la1[R2]);                         \
        la0[R3] = fmaf(W_lr[lw + 3], LE0(w), la0[R3]);                         \
        la1[R3] = fmaf(W_lr[lw + 3], LE1(w), la1[R3]);                         \
    }

    {
        const int ng = (wq < 3) ? 4 : 3;     // SGPR: groups of 4 regions (5 quads)
        for (int g = 0; g < 4; ++g) {
            if (g < ng) {                    // wave-uniform guard
                const int q0 = wq * 20 + g * 5;
                const int r = g << 2;
                // element t = 4*qi + comp (l = 80wq + 20g + t), region r + t/5
                DOQ(0, r + 0, r + 0, r + 0, r + 0)   // t 0..3
                DOQ(1, r + 0, r + 1, r + 1, r + 1)   // t 4..7
                DOQ(2, r + 1, r + 1, r + 2, r + 2)   // t 8..11
                DOQ(3, r + 2, r + 2, r + 2, r + 3)   // t 12..15
                DOQ(4, r + 3, r + 3, r + 3, r + 3)   // t 16..19
            }
        }
    }

    // combine global-branch partials across the 4 waves
    sgp[wq][lane] = make_float2((ga0 + ga1) + (ga2 + ga3), (gb0 + gb1) + (gb2 + gb3));
    __syncthreads();

    float gf0, gf1;
    {
        const float2 p0 = sgp[0][lane], p1 = sgp[1][lane];
        const float2 p2 = sgp[2][lane], p3 = sgp[3][lane];
        gf0 = RELU(((p0.x + p1.x) + (p2.x + p3.x)) + bgn);
        gf1 = RELU(((p0.y + p1.y) + (p2.y + p3.y)) + bgn);
    }

    // ---- stores: wave wq owns regions 16wq .. (16/16/16/12) ----
    float2* ob2 = (float2*)(out + (size_t)b * (60 * 128)) + lane;   // + s*64
    {
        const int ng = (wq < 3) ? 4 : 3;
        for (int g = 0; g < 4; ++g) {
            if (g < ng) {
                const int r = g << 2;
                const int s0 = wq * 16 + r;          // uniform -> b_lr scalar
                ob2[(s0 + 0) * 64] = make_float2(la0[r + 0] + gf0 + b_lr[s0 + 0],
                                                 la1[r + 0] + gf1 + b_lr[s0 + 0]);
                ob2[(s0 + 1) * 64] = make_float2(la0[r + 1] + gf0 + b_lr[s0 + 1],
                                                 la1[r + 1] + gf1 + b_lr[s0 + 1]);
                ob2[(s0 + 2) * 64] = make_float2(la0[r + 2] + gf0 + b_lr[s0 + 2],
                                                 la1[r + 2] + gf1 + b_lr[s0 + 2]);
                ob2[(s0 + 3) * 64] = make_float2(la0[r + 3] + gf0 + b_lr[s0 + 3],
                                                 la1[r + 3] + gf1 + b_lr[s0 + 3]);
            }
        }
    }
}

extern "C" void kernel_launch(void* const* d_in, const int* in_sizes, int n_in,
                              void* d_out, int out_size, void* d_ws, size_t ws_size,
                              hipStream_t stream) {
    const float* x    = (const float*)d_in[0];
    const float* W_le = (const float*)d_in[1];
    const float* b_le = (const float*)d_in[2];
    const float* W_lr = (const float*)d_in[3];
    const float* b_lr = (const float*)d_in[4];
    const float* W_ge = (const float*)d_in[5];
    const float* b_ge = (const float*)d_in[6];
    const float* W_gn = (const float*)d_in[7];
    const float* b_gn = (const float*)d_in[8];
    float* out = (float*)d_out;

    cle_kernel<<<4096, 256, 0, stream>>>(x, W_le, b_le, W_lr, b_lr,
                                         W_ge, b_ge, W_gn, b_gn, out);
}